// Round 12
// baseline (101.506 us; speedup 1.0000x reference)
//
#include <hip/hip_runtime.h>

#define NB 10   // labels 1..10
#define BATCH 8
#define EPSF 1e-6f

constexpr int THREADS          = 256;
constexpr int VEC_PER_BATCH    = (128 * 128 * 128) / 4;  // 524,288 float4 per batch
constexpr int BLOCKS_PER_BATCH = 64;
constexpr int GRID             = BLOCKS_PER_BATCH * BATCH; // 512 = 2 blocks/CU
constexpr int WAVE_VEC         = 2048;                     // float4 per wave (contiguous)
constexpr int STAGES           = WAVE_VEC / 64;            // 32 stages, 64 float4 each

// ws layout (4-byte units):
//   rows 0..29 : ws[idx*GRID + block]   partial sums (idx = which*10+lab; 0:I 1:X 2:T)
//   row 30     : presence mask per block (uint)
//   [31*GRID]  : completion counter (uint, memset to 0 each launch)
constexpr int CTR_OFF = 31 * GRID;

// async global->LDS DMA, 16B/lane: dest = wave-uniform base + lane*16 (linear),
// source = per-lane address. No VGPR destinations -> no spill fight.
__device__ __forceinline__ void dma16(const void* g, void* l) {
    __builtin_amdgcn_global_load_lds(
        (const __attribute__((address_space(1))) void*)g,
        (__attribute__((address_space(3))) void*)l, 16, 0, 0);
}

__global__ __launch_bounds__(THREADS)
void dice_fused(const float* __restrict__ x,
                const float* __restrict__ t,
                const int*   __restrict__ s,
                float* __restrict__ ws,
                float* __restrict__ out,
                unsigned* __restrict__ ctr)
{
    // per-wave private 4-deep ring buffers: no __syncthreads in main loop
    __shared__ float4 lx[4][4][64];   // [wave][buf][lane]
    __shared__ float4 lt[4][4][64];
    __shared__ int4   lsb[4][4][64];

    const int tid  = threadIdx.x;
    const int wave = tid >> 6, lane = tid & 63;
    const int batch = blockIdx.x >> 6;          // 64 blocks per batch
    const int sub   = blockIdx.x & 63;
    const long long chunk = (long long)batch * VEC_PER_BATCH
                          + (long long)(sub * 4 + wave) * WAVE_VEC;

    const float4* gx = (const float4*)x + chunk + lane;
    const float4* gt = (const float4*)t + chunk + lane;
    const int4*   gs = (const int4*)s  + chunk + lane;

    float aI[NB], aX[NB], aT[NB];
#pragma unroll
    for (int k = 0; k < NB; ++k) { aI[k] = 0.f; aX[k] = 0.f; aT[k] = 0.f; }
    unsigned bits = 0;   // bit v set <=> label value v seen

#define DO_ELEM(xe, te, se)                                     \
    do {                                                        \
        const float _x = (xe), _t = (te);                       \
        const int   _s = (se);                                  \
        const float _p = _x * _t;                               \
        bits |= (1u << _s);                                     \
        _Pragma("unroll")                                       \
        for (int k = 0; k < NB; ++k) {                          \
            const float m = (_s == k + 1) ? 1.0f : 0.0f;        \
            aI[k] = fmaf(m, _p, aI[k]);                         \
            aX[k] = fmaf(m, _x, aX[k]);                         \
            aT[k] = fmaf(m, _t, aT[k]);                         \
        }                                                       \
    } while (0)

    // prologue: DMA stages 0..2 (9 outstanding vmcnt events)
#pragma unroll
    for (int i = 0; i < 3; ++i) {
        dma16(gx + i * 64, &lx[wave][i][0]);
        dma16(gt + i * 64, &lt[wave][i][0]);
        dma16(gs + i * 64, &lsb[wave][i][0]);
    }
    const float4* px = gx + 3 * 64;   // prefetch pointers
    const float4* pt = gt + 3 * 64;
    const int4*   ps = gs + 3 * 64;

#pragma unroll 1
    for (int i = 0; i < STAGES; ++i) {
        // counted wait: stage i retired; stages i+1,i+2 (6 DMAs) stay in flight
        if (i <= STAGES - 3)      asm volatile("s_waitcnt vmcnt(6)" ::: "memory");
        else if (i == STAGES - 2) asm volatile("s_waitcnt vmcnt(3)" ::: "memory");
        else                      asm volatile("s_waitcnt vmcnt(0)" ::: "memory");
        __builtin_amdgcn_sched_barrier(0);

        if (i < STAGES - 3) {     // issue stage i+3 into the freed buffer
            const int nb = (i + 3) & 3;
            dma16(px, &lx[wave][nb][0]);
            dma16(pt, &lt[wave][nb][0]);
            dma16(ps, &lsb[wave][nb][0]);
            px += 64; pt += 64; ps += 64;
        }

        const int b = i & 3;      // consume stage i (3x ds_read_b128)
        const float4 xv = lx[wave][b][lane];
        const float4 tv = lt[wave][b][lane];
        const int4   sv = lsb[wave][b][lane];
        DO_ELEM(xv.x, tv.x, sv.x);
        DO_ELEM(xv.y, tv.y, sv.y);
        DO_ELEM(xv.z, tv.z, sv.z);
        DO_ELEM(xv.w, tv.w, sv.w);
    }
#undef DO_ELEM

    // wave-64 butterfly (once per block)
#pragma unroll
    for (int k = 0; k < NB; ++k) {
#pragma unroll
        for (int off = 32; off > 0; off >>= 1) {
            aI[k] += __shfl_xor(aI[k], off);
            aX[k] += __shfl_xor(aX[k], off);
            aT[k] += __shfl_xor(aT[k], off);
        }
    }
#pragma unroll
    for (int off = 32; off > 0; off >>= 1)
        bits |= (unsigned)__shfl_xor((int)bits, off);

    // cross-wave combine in LDS, then transposed plain stores
    __shared__ float    wsum[4][32];
    __shared__ unsigned wbm[4];
    if (lane < NB) {
        wsum[wave][lane]          = aI[lane];
        wsum[wave][NB + lane]     = aX[lane];
        wsum[wave][2 * NB + lane] = aT[lane];
    }
    if (lane == 0) wbm[wave] = bits;
    __syncthreads();

    if (tid < 3 * NB) {   // row idx = tid, column = blockIdx.x
        const float v = wsum[0][tid] + wsum[1][tid] + wsum[2][tid] + wsum[3][tid];
        ws[tid * GRID + blockIdx.x] = v;
    }
    if (tid == 0)
        ((unsigned*)ws)[3 * NB * GRID + blockIdx.x] = wbm[0] | wbm[1] | wbm[2] | wbm[3];

    // ---- last-block-done: canonical store -> fence -> barrier -> count ----
    __threadfence();                 // each thread's record stores device-visible
    __syncthreads();
    __shared__ unsigned amLast;
    if (tid == 0) amLast = (atomicAdd(ctr, 1u) == GRID - 1);
    __syncthreads();
    if (!amLast) return;
    __threadfence();                 // acquire side before reading all records

    // ---- finisher (last block only) ----
    __shared__ float    sums[BATCH * 3 * NB];   // [batch*30 + idx]
    __shared__ unsigned um[THREADS];

    // phase 1: 240 combos; 16 groups of 16 lanes, 15 combos each.
    // combo c: batch=c/30, idx=c%30 -> 64 contiguous floats at ws[idx*GRID+batch*64]
    const int grp = tid >> 4, l16 = tid & 15;
#pragma unroll
    for (int j = 0; j < 15; ++j) {
        const int c = grp + 16 * j;             // 0..239
        const int bb  = c / (3 * NB);
        const int idx = c % (3 * NB);
        const float4 v4 = *(const float4*)&ws[idx * GRID + bb * BLOCKS_PER_BATCH + l16 * 4];
        float v = v4.x + v4.y + v4.z + v4.w;
        v += __shfl_xor(v, 8);
        v += __shfl_xor(v, 4);
        v += __shfl_xor(v, 2);
        v += __shfl_xor(v, 1);
        if (l16 == 0) sums[c] = v;
    }

    // phase 2: OR all 512 presence masks
    const unsigned* mrow = (const unsigned*)ws + 3 * NB * GRID;
    um[tid] = mrow[tid] | mrow[tid + 256];
    __syncthreads();
    for (int st = THREADS / 2; st > 0; st >>= 1) {
        if (tid < st) um[tid] |= um[tid + st];
        __syncthreads();
    }
    const unsigned mask = um[0];   // bit v = label value v present (v=1..10)

    // phase 3: dice per label, reduce over labels (first wave only)
    if (tid < 64) {
        float lpb = 0.0f, pres = 0.0f;
        if (tid < NB) {
            float sum_loss = 0.0f, valid = 0.0f;
            for (int b = 0; b < BATCH; ++b) {
                const float I = sums[b * 3 * NB + tid];
                const float X = sums[b * 3 * NB + NB + tid];
                const float T = sums[b * 3 * NB + 2 * NB + tid];
                const float denom = X + T + 2.0f * EPSF;
                float bl = 1.0f - 2.0f * I / denom;
                if (T == 0.0f) bl = 0.0f; else valid += 1.0f;
                sum_loss += bl;
            }
            lpb  = sum_loss / fmaxf(valid, 1.0f);
            pres = ((mask >> (tid + 1)) & 1u) ? 1.0f : 0.0f;
        }
        float num = pres;
        float ls  = (pres > 0.0f) ? lpb : 0.0f;
#pragma unroll
        for (int off = 32; off > 0; off >>= 1) {
            num += __shfl_down(num, off);
            ls  += __shfl_down(ls,  off);
        }
        if (tid == 0) {
            out[0] = ls / num;
            out[1] = 0.0f;
        }
    }
}

extern "C" void kernel_launch(void* const* d_in, const int* in_sizes, int n_in,
                              void* d_out, int out_size, void* d_ws, size_t ws_size,
                              hipStream_t stream)
{
    const float* x = (const float*)d_in[0];
    const float* t = (const float*)d_in[1];
    const int*   s = (const int*)d_in[2];
    float* out = (float*)d_out;
    float* ws  = (float*)d_ws;
    unsigned* ctr = (unsigned*)ws + CTR_OFF;

    hipMemsetAsync(ctr, 0, sizeof(unsigned), stream);   // poison-proof, graph-safe
    dice_fused<<<GRID, THREADS, 0, stream>>>(x, t, s, ws, out, ctr);
}

// Round 13
// 46.259 us; speedup vs baseline: 2.1943x; 2.1943x over previous
//
#include <hip/hip_runtime.h>

#define NB 10   // labels 1..10
#define BATCH 8
#define EPSF 1e-6f

constexpr int THREADS        = 256;
constexpr int VEC_PER_BATCH  = (128 * 128 * 128) / 4;   // 524,288 float4 per batch
constexpr int BLOCKS_PER_BATCH = 64;
constexpr int GRID           = BLOCKS_PER_BATCH * BATCH; // 512 = 2 blocks/CU
constexpr int WAVE_VEC       = 2048;                     // float4 per wave (contiguous)
constexpr int STAGES         = WAVE_VEC / 64;            // 32 stages, 64 float4 each
// ws: one 32-float record per block: [0..9]=I,[10..19]=X,[20..29]=T,[30]=mask(uint)
constexpr int REC = 32;

// async global->LDS DMA, 16B per lane: dest = wave-uniform base + lane*16 (linear),
// source = per-lane address. No VGPR destinations -> no spill fight.
__device__ __forceinline__ void dma16(const void* g, void* l) {
    __builtin_amdgcn_global_load_lds(
        (const __attribute__((address_space(1))) void*)g,
        (__attribute__((address_space(3))) void*)l, 16, 0, 0);
}

__global__ __launch_bounds__(THREADS)
void dice_partial(const float* __restrict__ x,
                  const float* __restrict__ t,
                  const int*   __restrict__ s,
                  float* __restrict__ ws)
{
    // per-wave private 4-deep ring buffers: no __syncthreads needed in main loop
    __shared__ float4 lx[4][4][64];   // [wave][buf][lane]
    __shared__ float4 lt[4][4][64];
    __shared__ int4   lsb[4][4][64];

    const int tid  = threadIdx.x;
    const int wave = tid >> 6, lane = tid & 63;
    const int batch = blockIdx.x >> 6;          // 64 blocks per batch
    const int sub   = blockIdx.x & 63;
    const long long chunk = (long long)batch * VEC_PER_BATCH
                          + (long long)(sub * 4 + wave) * WAVE_VEC;

    const float4* gx = (const float4*)x + chunk + lane;
    const float4* gt = (const float4*)t + chunk + lane;
    const int4*   gs = (const int4*)s  + chunk + lane;

    float aI[NB], aX[NB], aT[NB];
#pragma unroll
    for (int k = 0; k < NB; ++k) { aI[k] = 0.f; aX[k] = 0.f; aT[k] = 0.f; }
    unsigned bits = 0;   // bit v set <=> label value v seen

#define DO_ELEM(xe, te, se)                                     \
    do {                                                        \
        const float _x = (xe), _t = (te);                       \
        const int   _s = (se);                                  \
        const float _p = _x * _t;                               \
        bits |= (1u << _s);                                     \
        _Pragma("unroll")                                       \
        for (int k = 0; k < NB; ++k) {                          \
            const float m = (_s == k + 1) ? 1.0f : 0.0f;        \
            aI[k] = fmaf(m, _p, aI[k]);                         \
            aX[k] = fmaf(m, _x, aX[k]);                         \
            aT[k] = fmaf(m, _t, aT[k]);                         \
        }                                                       \
    } while (0)

    // prologue: DMA stages 0..2 (9 outstanding vmcnt events)
#pragma unroll
    for (int i = 0; i < 3; ++i) {
        dma16(gx + i * 64, &lx[wave][i][0]);
        dma16(gt + i * 64, &lt[wave][i][0]);
        dma16(gs + i * 64, &lsb[wave][i][0]);
    }
    const float4* px = gx + 3 * 64;   // prefetch pointers
    const float4* pt = gt + 3 * 64;
    const int4*   ps = gs + 3 * 64;

#pragma unroll 1
    for (int i = 0; i < STAGES; ++i) {
        // counted wait: stage i retired; stages i+1,i+2 (6 DMAs) may stay in flight
        if (i <= STAGES - 3)      asm volatile("s_waitcnt vmcnt(6)" ::: "memory");
        else if (i == STAGES - 2) asm volatile("s_waitcnt vmcnt(3)" ::: "memory");
        else                      asm volatile("s_waitcnt vmcnt(0)" ::: "memory");
        __builtin_amdgcn_sched_barrier(0);

        if (i < STAGES - 3) {     // issue stage i+3 into the freed buffer
            const int nb = (i + 3) & 3;
            dma16(px, &lx[wave][nb][0]);
            dma16(pt, &lt[wave][nb][0]);
            dma16(ps, &lsb[wave][nb][0]);
            px += 64; pt += 64; ps += 64;
        }

        const int b = i & 3;      // consume stage i (3x ds_read_b128)
        const float4 xv = lx[wave][b][lane];
        const float4 tv = lt[wave][b][lane];
        const int4   sv = lsb[wave][b][lane];
        DO_ELEM(xv.x, tv.x, sv.x);
        DO_ELEM(xv.y, tv.y, sv.y);
        DO_ELEM(xv.z, tv.z, sv.z);
        DO_ELEM(xv.w, tv.w, sv.w);
    }
#undef DO_ELEM

    // wave-64 butterfly (once per block)
#pragma unroll
    for (int k = 0; k < NB; ++k) {
#pragma unroll
        for (int off = 32; off > 0; off >>= 1) {
            aI[k] += __shfl_xor(aI[k], off);
            aX[k] += __shfl_xor(aX[k], off);
            aT[k] += __shfl_xor(aT[k], off);
        }
    }
#pragma unroll
    for (int off = 32; off > 0; off >>= 1)
        bits |= (unsigned)__shfl_xor((int)bits, off);

    // cross-wave combine in LDS, then plain stores to this block's record
    __shared__ float    wsum[4][32];
    __shared__ unsigned wb[4];
    if (lane < NB) {
        wsum[wave][lane]          = aI[lane];
        wsum[wave][NB + lane]     = aX[lane];
        wsum[wave][2 * NB + lane] = aT[lane];
    }
    if (lane == 0) wb[wave] = bits;
    __syncthreads();

    if (tid < 3 * NB) {
        const float v = wsum[0][tid] + wsum[1][tid] + wsum[2][tid] + wsum[3][tid];
        ws[blockIdx.x * REC + tid] = v;
    }
    if (tid == 0)
        ((unsigned*)ws)[blockIdx.x * REC + 30] = wb[0] | wb[1] | wb[2] | wb[3];
}

__global__ void dice_final(const float* __restrict__ ws, float* __restrict__ out)
{
    const int tid = threadIdx.x;
    __shared__ float    sAll[BATCH][3 * NB];   // summed I/X/T per batch
    __shared__ unsigned um[THREADS];

    // phase 1: 240 combos (batch, which*10+lab) each sum 64 block records
    if (tid < BATCH * 3 * NB) {
        const int batch = tid / (3 * NB);
        const int idx   = tid % (3 * NB);
        float v = 0.0f;
        for (int j = 0; j < BLOCKS_PER_BATCH; ++j)
            v += ws[(batch * BLOCKS_PER_BATCH + j) * REC + idx];
        sAll[batch][idx] = v;
    }

    // phase 2: OR all presence masks
    unsigned m = 0;
#pragma unroll
    for (int j = 0; j < GRID / THREADS; ++j)
        m |= ((const unsigned*)ws)[(tid * (GRID / THREADS) + j) * REC + 30];
    um[tid] = m;
    __syncthreads();
    for (int st = THREADS / 2; st > 0; st >>= 1) {
        if (tid < st) um[tid] |= um[tid + st];
        __syncthreads();
    }
    const unsigned mask = um[0];   // bit v = label value v present (v=1..10)

    // phase 3: dice per label, then reduce over labels (first wave only)
    if (tid < 64) {
        float lpb = 0.0f, pres = 0.0f;
        if (tid < NB) {
            float sum_loss = 0.0f, valid = 0.0f;
            for (int b = 0; b < BATCH; ++b) {
                const float I = sAll[b][tid];
                const float X = sAll[b][NB + tid];
                const float T = sAll[b][2 * NB + tid];
                const float denom = X + T + 2.0f * EPSF;
                float bl = 1.0f - 2.0f * I / denom;
                if (T == 0.0f) bl = 0.0f; else valid += 1.0f;
                sum_loss += bl;
            }
            lpb  = sum_loss / fmaxf(valid, 1.0f);
            pres = ((mask >> (tid + 1)) & 1u) ? 1.0f : 0.0f;
        }
        float num = pres;
        float ls  = (pres > 0.0f) ? lpb : 0.0f;
#pragma unroll
        for (int off = 32; off > 0; off >>= 1) {
            num += __shfl_down(num, off);
            ls  += __shfl_down(ls,  off);
        }
        if (tid == 0) {
            out[0] = ls / num;
            out[1] = 0.0f;
        }
    }
}

extern "C" void kernel_launch(void* const* d_in, const int* in_sizes, int n_in,
                              void* d_out, int out_size, void* d_ws, size_t ws_size,
                              hipStream_t stream)
{
    const float* x = (const float*)d_in[0];
    const float* t = (const float*)d_in[1];
    const int*   s = (const int*)d_in[2];
    float* out = (float*)d_out;
    float* ws  = (float*)d_ws;

    dice_partial<<<GRID, THREADS, 0, stream>>>(x, t, s, ws);
    dice_final<<<1, THREADS, 0, stream>>>(ws, out);
}